// Round 3
// baseline (308.170 us; speedup 1.0000x reference)
//
#include <hip/hip_runtime.h>
#include <math.h>

#define EPSF 1e-7f
#define MAXNF (1.0f - 1e-5f)

__device__ __forceinline__ float wsum(float v) {
#pragma unroll
  for (int off = 32; off >= 1; off >>= 1) v += __shfl_xor(v, off, 64);
  return v;
}

// Reduce across each 32-lane half (masks <32 stay inside the half).
__device__ __forceinline__ float hsum32(float v) {
#pragma unroll
  for (int off = 16; off >= 1; off >>= 1) v += __shfl_xor(v, off, 64);
  return v;
}

__device__ __forceinline__ float dot4(const float4 a, const float4 b) {
  return a.x * b.x + a.y * b.y + a.z * b.z + a.w * b.w;
}

// One mobius_add step on a 256-dim vector, 4 elems/lane across a 64-lane wave.
__device__ __forceinline__ float4 mobius_step(const float4 x, const float4 y) {
  float px = wsum(dot4(x, x));
  float py = wsum(dot4(y, y));
  float pxy = wsum(dot4(x, y));
  float cx = 1.f + 2.f * pxy + py;
  float cy = 1.f - px;
  float inv = 1.f / fmaxf(1.f + 2.f * pxy + px * py, EPSF);
  float4 r;
  r.x = (cx * x.x + cy * y.x) * inv;
  r.y = (cx * x.y + cy * y.y) * inv;
  r.z = (cx * x.z + cy * y.z) * inv;
  r.w = (cx * x.w + cy * y.w) * inv;
  return r;
}

#define FMA4(ACC, S, BV)                                                      \
  ACC.x = fmaf(S, BV.x, ACC.x);                                               \
  ACC.y = fmaf(S, BV.y, ACC.y);                                               \
  ACC.z = fmaf(S, BV.z, ACC.z);                                               \
  ACC.w = fmaf(S, BV.w, ACC.w)

// Kernel 1: one 64-lane wave per (j,k) pair. Register-blocked 16x256 GEMM:
// lane (rg=l>>5, cg=l&31) owns rows rg*8..+8 x cols cg*8..+8. Feature operand
// comes from L1 via wave-broadcast global loads (same addr within a 32-lane
// half); W1 via coalesced loads (L2-resident). No LDS in the hot loop.
__global__ __launch_bounds__(64, 1) void
k1_h1(const float* __restrict__ features, const float* __restrict__ W1,
      const float* __restrict__ b1, const int* __restrict__ src_idx,
      const int* __restrict__ to_fetch, float* __restrict__ h1) {
  const int blk = blockIdx.x;  // j*16 + k
  const int j = blk >> 4;
  const int k = blk & 15;
  const int l = threadIdx.x;
  const int rg = l >> 5;
  const int cg = l & 31;

  __shared__ float trow[16][256];  // 16 KB, epilogue only
  __shared__ float s_fs2[16], s_ms2[16], s_srow[16];

  const int idxj = to_fetch[j] + (j << 10);
  const int a = src_idx[idxj * 16 + k];
  const float* fr[8];
#pragma unroll
  for (int i = 0; i < 8; ++i)
    fr[i] = features + (size_t)src_idx[a * 16 + rg * 8 + i] * 512;
  const float* wp = W1 + cg * 8;  // lane's 8-col base, row stride 256

  float4 acc0[8], acc1[8];
#pragma unroll
  for (int i = 0; i < 8; ++i) {
    acc0[i] = make_float4(0.f, 0.f, 0.f, 0.f);
    acc1[i] = make_float4(0.f, 0.f, 0.f, 0.f);
  }

  float4 Aa[8], Ba[8], Ab[8], Bb[8];

  auto loadA = [&](float4(&A)[8], int kx) {
#pragma unroll
    for (int i = 0; i < 8; ++i)
      A[i] = *reinterpret_cast<const float4*>(fr[i] + kx);
  };
  auto loadB = [&](float4(&B)[8], int kx) {
#pragma unroll
    for (int t = 0; t < 4; ++t) {
      B[t] = *reinterpret_cast<const float4*>(wp + (kx + t) * 256);
      B[t + 4] = *reinterpret_cast<const float4*>(wp + (kx + t) * 256 + 4);
    }
  };
  auto fmaset = [&](const float4(&A)[8], const float4(&B)[8]) {
#pragma unroll
    for (int i = 0; i < 8; ++i) {
      FMA4(acc0[i], A[i].x, B[0]);
      FMA4(acc1[i], A[i].x, B[4]);
      FMA4(acc0[i], A[i].y, B[1]);
      FMA4(acc1[i], A[i].y, B[5]);
      FMA4(acc0[i], A[i].z, B[2]);
      FMA4(acc1[i], A[i].z, B[6]);
      FMA4(acc0[i], A[i].w, B[3]);
      FMA4(acc1[i], A[i].w, B[7]);
    }
  };

  loadA(Aa, 0);
  loadB(Ba, 0);
  loadA(Ab, 4);
  loadB(Bb, 4);
#pragma unroll 1
  for (int kk = 0; kk < 512; kk += 8) {
    fmaset(Aa, Ba);
    loadA(Aa, (kk + 8) & 511);   // clamp keeps prefetch in-bounds
    loadB(Ba, (kk + 8) & 511);
    fmaset(Ab, Bb);
    loadA(Ab, (kk + 12) & 511);
    loadB(Bb, (kk + 12) & 511);
  }

  // ---- epilogue: row norms, mobius_matvec scale (0.25 folded in) ----
  float ms2l[8], fs2l[8];
#pragma unroll
  for (int i = 0; i < 8; ++i) {
    float p = dot4(acc0[i], acc0[i]) + dot4(acc1[i], acc1[i]);
    ms2l[i] = hsum32(p);
  }
#pragma unroll
  for (int i = 0; i < 8; ++i) {
    const float* p = fr[i] + cg * 16;  // lane's 16-float k-slice of row
    float s = 0.f;
#pragma unroll
    for (int t = 0; t < 4; ++t) {
      float4 f = *reinterpret_cast<const float4*>(p + 4 * t);
      s += dot4(f, f);
    }
    fs2l[i] = hsum32(s);
  }
  if (cg == 0) {
#pragma unroll
    for (int i = 0; i < 8; ++i) {
      s_ms2[rg * 8 + i] = ms2l[i];
      s_fs2[rg * 8 + i] = fs2l[i];
    }
  }
  __syncthreads();
  if (l < 16) {
    float xn = fminf(fmaxf(0.25f * sqrtf(s_fs2[l]), EPSF), MAXNF);
    float mxn = fmaxf(0.25f * sqrtf(s_ms2[l]), EPSF);
    s_srow[l] = tanhf(mxn / xn * atanhf(xn)) * 0.25f / mxn;
  }
  __syncthreads();
#pragma unroll
  for (int i = 0; i < 8; ++i) {
    const float s = s_srow[rg * 8 + i];
    float4 t0, t1;
    t0.x = acc0[i].x * s; t0.y = acc0[i].y * s;
    t0.z = acc0[i].z * s; t0.w = acc0[i].w * s;
    t1.x = acc1[i].x * s; t1.y = acc1[i].y * s;
    t1.z = acc1[i].z * s; t1.w = acc1[i].w * s;
    *reinterpret_cast<float4*>(&trow[rg * 8 + i][cg * 8]) = t0;
    *reinterpret_cast<float4*>(&trow[rg * 8 + i][cg * 8 + 4]) = t1;
  }
  __syncthreads();

  // ---- chained mobius_add over the 16 rows, whole wave ----
  const int l4 = l << 2;
  float4 x = *reinterpret_cast<const float4*>(&trow[0][l4]);
#pragma unroll 1
  for (int kk = 1; kk < 16; ++kk) {
    const float4 y = *reinterpret_cast<const float4*>(&trow[kk][l4]);
    x = mobius_step(x, y);
  }
  x.x *= 0.25f; x.y *= 0.25f; x.z *= 0.25f; x.w *= 0.25f;
  {
    const float4 b = *reinterpret_cast<const float4*>(b1 + l4);
    x = mobius_step(x, b);
  }
  // expmap0(relu(logmap0(x)))
  float pn = wsum(dot4(x, x));
  float yn = fminf(fmaxf(sqrtf(pn), EPSF), MAXNF);
  float s = atanhf(yn) / yn;
  float4 v;
  v.x = fmaxf(s * x.x, 0.f);
  v.y = fmaxf(s * x.y, 0.f);
  v.z = fmaxf(s * x.z, 0.f);
  v.w = fmaxf(s * x.w, 0.f);
  float pv = wsum(dot4(v, v));
  float vn = fmaxf(sqrtf(pv), EPSF);
  float s2 = tanhf(vn) / vn;
  float4 h;
  h.x = s2 * v.x;
  h.y = s2 * v.y;
  h.z = s2 * v.z;
  h.w = s2 * v.w;
  *reinterpret_cast<float4*>(h1 + (size_t)blk * 256 + l4) = h;
}

// Kernel 2: one wave per output row j. Layer-2 aggregate+matvec+nonlinearity,
// then layer-3 classifier.
__global__ __launch_bounds__(64) void
k2_out(const float* __restrict__ h1, const float* __restrict__ W2,
       const float* __restrict__ b2, const float* __restrict__ Wl,
       const float* __restrict__ bl, float* __restrict__ out) {
  const int j = blockIdx.x;
  const int l = threadIdx.x;
  const int l4 = l << 2;
  __shared__ float xs[256];

  const float* base = h1 + (size_t)j * 16 * 256;
  float4 x = *reinterpret_cast<const float4*>(base + l4);
  x.x *= 0.25f; x.y *= 0.25f; x.z *= 0.25f; x.w *= 0.25f;
#pragma unroll 1
  for (int kk = 1; kk < 16; ++kk) {
    float4 y = *reinterpret_cast<const float4*>(base + kk * 256 + l4);
    y.x *= 0.25f; y.y *= 0.25f; y.z *= 0.25f; y.w *= 0.25f;
    x = mobius_step(x, y);
  }

  // mobius_matvec(x, W2): mx[n] = sum_d x[d] * W2[d][n]
  *reinterpret_cast<float4*>(&xs[l4]) = x;
  __syncthreads();
  float4 mx = make_float4(0.f, 0.f, 0.f, 0.f);
  for (int d = 0; d < 256; ++d) {
    const float xd = xs[d];
    const float4 w = *reinterpret_cast<const float4*>(W2 + d * 256 + l4);
    mx.x = fmaf(xd, w.x, mx.x);
    mx.y = fmaf(xd, w.y, mx.y);
    mx.z = fmaf(xd, w.z, mx.z);
    mx.w = fmaf(xd, w.w, mx.w);
  }
  {
    float px = wsum(dot4(x, x));
    float pm = wsum(dot4(mx, mx));
    float xn = fminf(fmaxf(sqrtf(px), EPSF), MAXNF);
    float mxn = fmaxf(sqrtf(pm), EPSF);
    float s = tanhf(mxn / xn * atanhf(xn)) / mxn;
    s *= 0.25f;  // rst * norm
    x.x = s * mx.x; x.y = s * mx.y; x.z = s * mx.z; x.w = s * mx.w;
  }
  {
    const float4 b = *reinterpret_cast<const float4*>(b2 + l4);
    x = mobius_step(x, b);
  }
  float pn = wsum(dot4(x, x));
  float yn = fminf(fmaxf(sqrtf(pn), EPSF), MAXNF);
  float s = atanhf(yn) / yn;
  float4 v;
  v.x = fmaxf(s * x.x, 0.f);
  v.y = fmaxf(s * x.y, 0.f);
  v.z = fmaxf(s * x.z, 0.f);
  v.w = fmaxf(s * x.w, 0.f);
  float pv = wsum(dot4(v, v));
  float vn = fmaxf(sqrtf(pv), EPSF);
  float s2 = tanhf(vn) / vn;
  float4 h;
  h.x = s2 * v.x; h.y = s2 * v.y; h.z = s2 * v.z; h.w = s2 * v.w;

  // Layer 3: mx2[o] = sum_d h[d] * Wl[o][d], o = lane.
  __syncthreads();
  *reinterpret_cast<float4*>(&xs[l4]) = h;
  __syncthreads();
  float m = 0.f;
  for (int d = 0; d < 256; d += 4) {
    const float4 w = *reinterpret_cast<const float4*>(Wl + (size_t)l * 256 + d);
    m = fmaf(w.x, xs[d + 0], m);
    m = fmaf(w.y, xs[d + 1], m);
    m = fmaf(w.z, xs[d + 2], m);
    m = fmaf(w.w, xs[d + 3], m);
  }
  float ph = wsum(dot4(h, h));
  float pmm = wsum(m * m);
  float hn = fminf(fmaxf(sqrtf(ph), EPSF), MAXNF);
  float mn = fmaxf(sqrtf(pmm), EPSF);
  float sc = tanhf(mn / hn * atanhf(hn)) / mn;
  float mo = sc * m;
  float bo = bl[l];
  float pxx = wsum(mo * mo);
  float pbb = wsum(bo * bo);
  float pxb = wsum(mo * bo);
  float cx = 1.f + 2.f * pxb + pbb;
  float cy = 1.f - pxx;
  float inv = 1.f / fmaxf(1.f + 2.f * pxb + pxx * pbb, EPSF);
  out[j * 64 + l] = (cx * mo + cy * bo) * inv;
}

extern "C" void kernel_launch(void* const* d_in, const int* in_sizes, int n_in,
                              void* d_out, int out_size, void* d_ws,
                              size_t ws_size, hipStream_t stream) {
  const float* features = (const float*)d_in[0];
  const float* W1 = (const float*)d_in[1];
  const float* b1 = (const float*)d_in[2];
  const float* W2 = (const float*)d_in[3];
  const float* b2 = (const float*)d_in[4];
  const float* Wl = (const float*)d_in[5];
  const float* bl = (const float*)d_in[6];
  const int* src_idx = (const int*)d_in[7];
  const int* to_fetch = (const int*)d_in[8];
  float* out = (float*)d_out;
  float* h1 = (float*)d_ws;  // 1024 * 256 floats = 1 MB scratch

  k1_h1<<<1024, 64, 0, stream>>>(features, W1, b1, src_idx, to_fetch, h1);
  k2_out<<<64, 64, 0, stream>>>(h1, W2, b2, Wl, bl, out);
}

// Round 4
// 156.839 us; speedup vs baseline: 1.9649x; 1.9649x over previous
//
#include <hip/hip_runtime.h>
#include <math.h>

#define EPSF 1e-7f
#define MAXNF (1.0f - 1e-5f)

__device__ __forceinline__ float wsum(float v) {
#pragma unroll
  for (int off = 32; off >= 1; off >>= 1) v += __shfl_xor(v, off, 64);
  return v;
}

// Reduce across each 32-lane half.
__device__ __forceinline__ float hsum32(float v) {
#pragma unroll
  for (int off = 16; off >= 1; off >>= 1) v += __shfl_xor(v, off, 64);
  return v;
}

__device__ __forceinline__ float dot4(const float4 a, const float4 b) {
  return a.x * b.x + a.y * b.y + a.z * b.z + a.w * b.w;
}

// One mobius_add step on a 256-dim vector, 4 elems/lane across a 64-lane wave.
__device__ __forceinline__ float4 mobius_step(const float4 x, const float4 y) {
  float px = wsum(dot4(x, x));
  float py = wsum(dot4(y, y));
  float pxy = wsum(dot4(x, y));
  float cx = 1.f + 2.f * pxy + py;
  float cy = 1.f - px;
  float inv = 1.f / fmaxf(1.f + 2.f * pxy + px * py, EPSF);
  float4 r;
  r.x = (cx * x.x + cy * y.x) * inv;
  r.y = (cx * x.y + cy * y.y) * inv;
  r.z = (cx * x.z + cy * y.z) * inv;
  r.w = (cx * x.w + cy * y.w) * inv;
  return r;
}

#define FMA4(ACC, S, BV)                                                      \
  ACC.x = fmaf(S, BV.x, ACC.x);                                               \
  ACC.y = fmaf(S, BV.y, ACC.y);                                               \
  ACC.z = fmaf(S, BV.z, ACC.z);                                               \
  ACC.w = fmaf(S, BV.w, ACC.w)

// Kernel 1: block = (j,k) pair, 256 threads (4 waves), 4 blocks/CU.
// Tile: 16 rows x 256 cols, per-thread 2 rows x 8 cols.
// A (scaled feat) from LDS via wave-broadcast b128 (2 distinct addrs/instr =
// free); W1 from global (L1/L2-resident, halves deduplicate). 64 FMAs per
// 2 LDS instr per 4-k -> FMA-bound, LDS pipe ~50%.
__global__ __launch_bounds__(256, 4) void
k1_h1(const float* __restrict__ features, const float* __restrict__ W1,
      const float* __restrict__ b1, const int* __restrict__ src_idx,
      const int* __restrict__ to_fetch, float* __restrict__ h1) {
  const int blk = blockIdx.x;  // j*16 + k
  const int j = blk >> 4;
  const int k = blk & 15;
  const int tid = threadIdx.x;

  __shared__ float feat[16][512];  // 32 KB; first 16 KB reused as trow[16][256]
  __shared__ float s_fs2[16], s_ms2[16], s_srow[16];
  __shared__ int s_vnode[16];
  __shared__ int s_a;

  if (tid == 0) {
    int idxj = to_fetch[j] + (j << 10);
    s_a = src_idx[idxj * 16 + k];
  }
  __syncthreads();
  if (tid < 16) s_vnode[tid] = src_idx[s_a * 16 + tid];
  __syncthreads();

  // Stage 16 rows x 512, scaled by K^-0.5 = 0.25. Coalesced float4.
#pragma unroll
  for (int i = 0; i < 8; ++i) {
    int slot = (i << 8) + tid;       // 0..2047
    int r = slot >> 7;               // 128 float4 per row
    int c4 = (slot & 127) << 2;
    const float4 f = *reinterpret_cast<const float4*>(
        features + (size_t)s_vnode[r] * 512 + c4);
    float4 g;
    g.x = 0.25f * f.x; g.y = 0.25f * f.y;
    g.z = 0.25f * f.z; g.w = 0.25f * f.w;
    *reinterpret_cast<float4*>(&feat[r][c4]) = g;
  }
  __syncthreads();

  // GEMM: acc[2 rows][8 cols]. r0 = 0,2,..,14 per 32-lane half; c0 = 8*lane32.
  const int r0 = (tid >> 5) << 1;
  const int c0 = (tid & 31) << 3;
  float4 acc00 = make_float4(0.f, 0.f, 0.f, 0.f);
  float4 acc01 = make_float4(0.f, 0.f, 0.f, 0.f);
  float4 acc10 = make_float4(0.f, 0.f, 0.f, 0.f);
  float4 acc11 = make_float4(0.f, 0.f, 0.f, 0.f);
  const float* W1p = W1 + c0;

#pragma unroll 2
  for (int kk = 0; kk < 512; kk += 4) {
    const float4 a0 = *reinterpret_cast<const float4*>(&feat[r0][kk]);
    const float4 a1 = *reinterpret_cast<const float4*>(&feat[r0 + 1][kk]);
    const float* wp = W1p + kk * 256;
    float4 b0[4], b4[4];
#pragma unroll
    for (int t = 0; t < 4; ++t) {
      b0[t] = *reinterpret_cast<const float4*>(wp + t * 256);
      b4[t] = *reinterpret_cast<const float4*>(wp + t * 256 + 4);
    }
    FMA4(acc00, a0.x, b0[0]); FMA4(acc01, a0.x, b4[0]);
    FMA4(acc10, a1.x, b0[0]); FMA4(acc11, a1.x, b4[0]);
    FMA4(acc00, a0.y, b0[1]); FMA4(acc01, a0.y, b4[1]);
    FMA4(acc10, a1.y, b0[1]); FMA4(acc11, a1.y, b4[1]);
    FMA4(acc00, a0.z, b0[2]); FMA4(acc01, a0.z, b4[2]);
    FMA4(acc10, a1.z, b0[2]); FMA4(acc11, a1.z, b4[2]);
    FMA4(acc00, a0.w, b0[3]); FMA4(acc01, a0.w, b4[3]);
    FMA4(acc10, a1.w, b0[3]); FMA4(acc11, a1.w, b4[3]);
  }

  // ms2[r] = ||mx row||^2: reduce per-thread 8-col partials over 32 lanes.
  {
    float m0 = dot4(acc00, acc00) + dot4(acc01, acc01);
    float m1 = dot4(acc10, acc10) + dot4(acc11, acc11);
    m0 = hsum32(m0);
    m1 = hsum32(m1);
    if ((tid & 31) == 0) {
      s_ms2[r0] = m0;
      s_ms2[r0 + 1] = m1;
    }
  }
  // fs2[r] = ||x row||^2 (scaled feat): wave w handles rows 4w..4w+3.
  {
    const int w = tid >> 6, lane = tid & 63;
#pragma unroll
    for (int rr = 0; rr < 4; ++rr) {
      const int r = (w << 2) + rr;
      float s = 0.f;
#pragma unroll
      for (int c = 0; c < 512; c += 64) {
        float v = feat[r][c + lane];
        s = fmaf(v, v, s);
      }
      s = wsum(s);
      if (lane == 0) s_fs2[r] = s;
    }
  }
  __syncthreads();
  if (tid < 16) {
    float xn = fminf(fmaxf(sqrtf(s_fs2[tid]), EPSF), MAXNF);
    float mxn = fmaxf(sqrtf(s_ms2[tid]), EPSF);
    s_srow[tid] = tanhf(mxn / xn * atanhf(xn)) / mxn;
  }
  __syncthreads();

  // Scale and write transformed rows into reused LDS (trow = feat[0..7][*]).
  float (*trow)[256] = reinterpret_cast<float(*)[256]>(&feat[0][0]);
  {
    const float s0 = s_srow[r0];
    const float s1 = s_srow[r0 + 1];
    float4 t;
    t.x = acc00.x * s0; t.y = acc00.y * s0; t.z = acc00.z * s0; t.w = acc00.w * s0;
    *reinterpret_cast<float4*>(&trow[r0][c0]) = t;
    t.x = acc01.x * s0; t.y = acc01.y * s0; t.z = acc01.z * s0; t.w = acc01.w * s0;
    *reinterpret_cast<float4*>(&trow[r0][c0 + 4]) = t;
    t.x = acc10.x * s1; t.y = acc10.y * s1; t.z = acc10.z * s1; t.w = acc10.w * s1;
    *reinterpret_cast<float4*>(&trow[r0 + 1][c0]) = t;
    t.x = acc11.x * s1; t.y = acc11.y * s1; t.z = acc11.z * s1; t.w = acc11.w * s1;
    *reinterpret_cast<float4*>(&trow[r0 + 1][c0 + 4]) = t;
  }
  __syncthreads();

  // Chained mobius_add over the 16 rows, wave 0 only.
  if (tid < 64) {
    const int l4 = tid << 2;
    float4 x = *reinterpret_cast<const float4*>(&trow[0][l4]);
#pragma unroll 1
    for (int kk = 1; kk < 16; ++kk) {
      const float4 y = *reinterpret_cast<const float4*>(&trow[kk][l4]);
      x = mobius_step(x, y);
    }
    x.x *= 0.25f; x.y *= 0.25f; x.z *= 0.25f; x.w *= 0.25f;
    {
      const float4 b = *reinterpret_cast<const float4*>(b1 + l4);
      x = mobius_step(x, b);
    }
    // expmap0(relu(logmap0(x)))
    float pn = wsum(dot4(x, x));
    float yn = fminf(fmaxf(sqrtf(pn), EPSF), MAXNF);
    float s = atanhf(yn) / yn;
    float4 v;
    v.x = fmaxf(s * x.x, 0.f);
    v.y = fmaxf(s * x.y, 0.f);
    v.z = fmaxf(s * x.z, 0.f);
    v.w = fmaxf(s * x.w, 0.f);
    float pv = wsum(dot4(v, v));
    float vn = fmaxf(sqrtf(pv), EPSF);
    float s2 = tanhf(vn) / vn;
    float4 h;
    h.x = s2 * v.x;
    h.y = s2 * v.y;
    h.z = s2 * v.z;
    h.w = s2 * v.w;
    *reinterpret_cast<float4*>(h1 + (size_t)blk * 256 + l4) = h;
  }
}

// Kernel 2: one wave per output row j. Layer-2 aggregate+matvec+nonlinearity,
// then layer-3 classifier.
__global__ __launch_bounds__(64) void
k2_out(const float* __restrict__ h1, const float* __restrict__ W2,
       const float* __restrict__ b2, const float* __restrict__ Wl,
       const float* __restrict__ bl, float* __restrict__ out) {
  const int j = blockIdx.x;
  const int l = threadIdx.x;
  const int l4 = l << 2;
  __shared__ float xs[256];

  const float* base = h1 + (size_t)j * 16 * 256;
  float4 x = *reinterpret_cast<const float4*>(base + l4);
  x.x *= 0.25f; x.y *= 0.25f; x.z *= 0.25f; x.w *= 0.25f;
#pragma unroll 1
  for (int kk = 1; kk < 16; ++kk) {
    float4 y = *reinterpret_cast<const float4*>(base + kk * 256 + l4);
    y.x *= 0.25f; y.y *= 0.25f; y.z *= 0.25f; y.w *= 0.25f;
    x = mobius_step(x, y);
  }

  // mobius_matvec(x, W2): mx[n] = sum_d x[d] * W2[d][n]
  *reinterpret_cast<float4*>(&xs[l4]) = x;
  __syncthreads();
  float4 mx = make_float4(0.f, 0.f, 0.f, 0.f);
  for (int d = 0; d < 256; ++d) {
    const float xd = xs[d];
    const float4 w = *reinterpret_cast<const float4*>(W2 + d * 256 + l4);
    mx.x = fmaf(xd, w.x, mx.x);
    mx.y = fmaf(xd, w.y, mx.y);
    mx.z = fmaf(xd, w.z, mx.z);
    mx.w = fmaf(xd, w.w, mx.w);
  }
  {
    float px = wsum(dot4(x, x));
    float pm = wsum(dot4(mx, mx));
    float xn = fminf(fmaxf(sqrtf(px), EPSF), MAXNF);
    float mxn = fmaxf(sqrtf(pm), EPSF);
    float s = tanhf(mxn / xn * atanhf(xn)) / mxn;
    s *= 0.25f;  // rst * norm
    x.x = s * mx.x; x.y = s * mx.y; x.z = s * mx.z; x.w = s * mx.w;
  }
  {
    const float4 b = *reinterpret_cast<const float4*>(b2 + l4);
    x = mobius_step(x, b);
  }
  float pn = wsum(dot4(x, x));
  float yn = fminf(fmaxf(sqrtf(pn), EPSF), MAXNF);
  float s = atanhf(yn) / yn;
  float4 v;
  v.x = fmaxf(s * x.x, 0.f);
  v.y = fmaxf(s * x.y, 0.f);
  v.z = fmaxf(s * x.z, 0.f);
  v.w = fmaxf(s * x.w, 0.f);
  float pv = wsum(dot4(v, v));
  float vn = fmaxf(sqrtf(pv), EPSF);
  float s2 = tanhf(vn) / vn;
  float4 h;
  h.x = s2 * v.x; h.y = s2 * v.y; h.z = s2 * v.z; h.w = s2 * v.w;

  // Layer 3: mx2[o] = sum_d h[d] * Wl[o][d], o = lane.
  __syncthreads();
  *reinterpret_cast<float4*>(&xs[l4]) = h;
  __syncthreads();
  float m = 0.f;
  for (int d = 0; d < 256; d += 4) {
    const float4 w = *reinterpret_cast<const float4*>(Wl + (size_t)l * 256 + d);
    m = fmaf(w.x, xs[d + 0], m);
    m = fmaf(w.y, xs[d + 1], m);
    m = fmaf(w.z, xs[d + 2], m);
    m = fmaf(w.w, xs[d + 3], m);
  }
  float ph = wsum(dot4(h, h));
  float pmm = wsum(m * m);
  float hn = fminf(fmaxf(sqrtf(ph), EPSF), MAXNF);
  float mn = fmaxf(sqrtf(pmm), EPSF);
  float sc = tanhf(mn / hn * atanhf(hn)) / mn;
  float mo = sc * m;
  float bo = bl[l];
  float pxx = wsum(mo * mo);
  float pbb = wsum(bo * bo);
  float pxb = wsum(mo * bo);
  float cx = 1.f + 2.f * pxb + pbb;
  float cy = 1.f - pxx;
  float inv = 1.f / fmaxf(1.f + 2.f * pxb + pxx * pbb, EPSF);
  out[j * 64 + l] = (cx * mo + cy * bo) * inv;
}

extern "C" void kernel_launch(void* const* d_in, const int* in_sizes, int n_in,
                              void* d_out, int out_size, void* d_ws,
                              size_t ws_size, hipStream_t stream) {
  const float* features = (const float*)d_in[0];
  const float* W1 = (const float*)d_in[1];
  const float* b1 = (const float*)d_in[2];
  const float* W2 = (const float*)d_in[3];
  const float* b2 = (const float*)d_in[4];
  const float* Wl = (const float*)d_in[5];
  const float* bl = (const float*)d_in[6];
  const int* src_idx = (const int*)d_in[7];
  const int* to_fetch = (const int*)d_in[8];
  float* out = (float*)d_out;
  float* h1 = (float*)d_ws;  // 1024 * 256 floats = 1 MB scratch

  k1_h1<<<1024, 256, 0, stream>>>(features, W1, b1, src_idx, to_fetch, h1);
  k2_out<<<64, 64, 0, stream>>>(h1, W2, b2, Wl, bl, out);
}